// Round 5
// baseline (151.920 us; speedup 1.0000x reference)
//
#include <hip/hip_runtime.h>

#define B_ 512
#define L_ 8192
#define N_ 128
#define S_ 256
#define DELIM_ 5
#define T_ 1024          // threads per block (16 waves) -> 2 blocks/CU = 32 waves/CU (full)
#define NW_ (T_ / 64)    // 16 waves per block
#define PER_ (L_ / T_)   // 8 tokens per thread in scan phase

typedef float v4f __attribute__((ext_vector_type(4)));  // native vec: OK for nontemporal builtin

// One block per row. Phase 1: delimiter scan -> chunk table in LDS.
// Phase 2: one sentence per wave per iteration (64 lanes x 4 elems = S=256),
// nontemporal float4 stores, ballot+popc for len_sent (scalar pipe, short
// dep chain), no barriers/atomics in the loop.
__global__ __launch_bounds__(T_) void split_kernel(const int* __restrict__ x,
                                                   float* __restrict__ otp,
                                                   float* __restrict__ len_doc,
                                                   float* __restrict__ mask) {
    const int b = blockIdx.x;
    const int t = threadIdx.x;
    const int lane = t & 63;
    const int w = t >> 6;
    const int* __restrict__ row = x + (size_t)b * L_;

    __shared__ int s_wsum[NW_];
    __shared__ int s_dpos[N_ - 1];  // first 127 delimiter positions (tail merge)
    __shared__ int s_start[N_];
    __shared__ int s_cl[N_];        // copy length: 0 for empty/unused, else min(size, S)
    __shared__ int s_doc[NW_];

    // ---- phase 1a: count delimiters in this thread's contiguous slice ----
    const int base = t * PER_;
    int c = 0;
#pragma unroll
    for (int i = 0; i < PER_; ++i) c += (row[base + i] == DELIM_);

    // wave inclusive scan
    int v = c;
#pragma unroll
    for (int d = 1; d < 64; d <<= 1) {
        int n = __shfl_up(v, d, 64);
        if (lane >= d) v += n;
    }
    if (lane == 63) s_wsum[w] = v;
    __syncthreads();

    int woff = 0, m = 0;
#pragma unroll
    for (int i = 0; i < NW_; ++i) {
        const int sv = s_wsum[i];
        if (i < w) woff += sv;
        m += sv;  // total delimiters in row
    }
    const int off = woff + v - c;  // exclusive prefix for this thread

    // ---- phase 1b: emit ordered delimiter positions (only first N-1 matter) ----
    if (c > 0 && off < N_ - 1) {
        int o = off;
        for (int i = 0; i < PER_; ++i) {
            if (row[base + i] == DELIM_) {
                if (o < N_ - 1) s_dpos[o] = base + i;
                ++o;
            }
        }
    }
    __syncthreads();

    // ---- phase 1c: chunk table ----
    if (t < N_) {
        const int k = t;
        const int mc = (m < N_ - 1) ? m : (N_ - 1);  // last used chunk index
        int start = 0, cl = 0;
        if (k <= mc) {
            start = (k == 0) ? 0 : (s_dpos[k - 1] + 1);
            const int end = (k < mc) ? s_dpos[k] : L_;  // rpad[L] = trailing DELIM
            const int size = end - start + 1;           // delimiter belongs to its chunk
            cl = (size <= 1) ? 0 : (size < S_ ? size : S_);  // lone delim -> all PAD
        }
        s_start[k] = start;
        s_cl[k] = cl;
    }
    __syncthreads();

    // ---- phase 2: wave w handles sentence k = i*NW_ + w (8 iterations) ----
    float* __restrict__ otp_b = otp + (size_t)b * N_ * S_;
    float* __restrict__ msk_b = mask + (size_t)b * N_ * S_;
    int doccnt = 0;
#pragma unroll
    for (int i = 0; i < (N_ / NW_); ++i) {
        const int k = i * NW_ + w;
        const int start = s_start[k];  // wave-uniform LDS broadcast
        const int cl = s_cl[k];
        const int s0 = lane * 4;
        float tf[4];
        int len = 0;
#pragma unroll
        for (int j = 0; j < 4; ++j) {
            const int e = s0 + j;
            int tok = 0;
            if (e < cl) {
                const int g = start + e;
                tok = (g < L_) ? row[g] : DELIM_;  // L1/L2 hit: row read in phase 1
            }
            tf[j] = (float)tok;
            // ballot+popc: wave-uniform count, scalar pipe, no shfl chain
            len += __popcll(__ballot(tok != 0));
        }

        v4f ov = {tf[0], tf[1], tf[2], tf[3]};
        v4f mv = {s0 < len ? 1.0f : 0.0f, s0 + 1 < len ? 1.0f : 0.0f,
                  s0 + 2 < len ? 1.0f : 0.0f, s0 + 3 < len ? 1.0f : 0.0f};
        __builtin_nontemporal_store(ov, (v4f*)(otp_b + (size_t)k * S_ + s0));
        __builtin_nontemporal_store(mv, (v4f*)(msk_b + (size_t)k * S_ + s0));
        doccnt += (len > 0);
    }

    // ---- len_doc: one LDS reduction per block, no atomics ----
    if (lane == 0) s_doc[w] = doccnt;
    __syncthreads();
    if (t == 0) {
        int d = 0;
#pragma unroll
        for (int i = 0; i < NW_; ++i) d += s_doc[i];
        len_doc[b] = (float)d;
    }
}

extern "C" void kernel_launch(void* const* d_in, const int* in_sizes, int n_in,
                              void* d_out, int out_size, void* d_ws, size_t ws_size,
                              hipStream_t stream) {
    const int* x = (const int*)d_in[0];
    float* out = (float*)d_out;

    // d_out layout (flat, return order): otp[B*N*S] | len_doc[B] | mask[B*N*S]
    float* otp = out;
    float* len_doc = out + (size_t)B_ * N_ * S_;
    float* mask = len_doc + B_;

    split_kernel<<<B_, T_, 0, stream>>>(x, otp, len_doc, mask);
}

// Round 6
// 142.489 us; speedup vs baseline: 1.0662x; 1.0662x over previous
//
#include <hip/hip_runtime.h>

#define B_ 512
#define L_ 8192
#define N_ 128
#define S_ 256
#define DELIM_ 5
#define T_ 1024          // 16 waves/block, 2 blocks/CU -> 32 waves/CU
#define NW_ (T_ / 64)

// One block per row.
// Phase 1: coalesced int4 row read (kept in registers), packed block scan ->
//          ordered delimiter positions -> chunk table in LDS.
// Phase 2: one sentence per wave per iteration (64 lanes x 4 = S), gathers hit
//          L1/L2 (row just read), plain float4 stores (NT regressed in R5),
//          ballot+popc for len_sent. No atomics.
__global__ __launch_bounds__(T_) void split_kernel(const int* __restrict__ x,
                                                   float* __restrict__ otp,
                                                   float* __restrict__ len_doc,
                                                   float* __restrict__ mask) {
    const int b = blockIdx.x;
    const int t = threadIdx.x;
    const int lane = t & 63;
    const int w = t >> 6;
    const int* __restrict__ row = x + (size_t)b * L_;

    __shared__ int s_wsum[NW_];
    __shared__ int s_dpos[N_ - 1];  // first 127 delimiter positions (tail merge)
    __shared__ int s_start[N_];
    __shared__ int s_cl[N_];        // copy length: 0 for empty/unused, else min(size, S)
    __shared__ int s_doc[NW_];

    // ---- phase 1a: coalesced int4 loads; two ordered chunks of 4096 tokens ----
    // chunk0: tokens [4t, 4t+4)         (t = 0..1023)
    // chunk1: tokens [4096 + 4t, +4)
    const int4 r0 = ((const int4*)row)[t];
    const int4 r1 = ((const int4*)row)[t + T_];
    const int c0 = (r0.x == DELIM_) + (r0.y == DELIM_) + (r0.z == DELIM_) + (r0.w == DELIM_);
    const int c1 = (r1.x == DELIM_) + (r1.y == DELIM_) + (r1.z == DELIM_) + (r1.w == DELIM_);
    const int packed = c0 | (c1 << 16);  // max 8192 per half: fits 16 bits

    // wave inclusive scan of packed counts
    int v = packed;
#pragma unroll
    for (int d = 1; d < 64; d <<= 1) {
        int n = __shfl_up(v, d, 64);
        if (lane >= d) v += n;
    }
    if (lane == 63) s_wsum[w] = v;
    __syncthreads();

    int woff = 0, tot = 0;
#pragma unroll
    for (int i = 0; i < NW_; ++i) {
        const int sv = s_wsum[i];
        if (i < w) woff += sv;
        tot += sv;
    }
    const int pre = woff + v - packed;          // exclusive prefix (packed)
    const int c0tot = tot & 0xffff;             // total delims in chunk0
    const int m = c0tot + (tot >> 16);          // total delims in row
    const int off0 = pre & 0xffff;              // rank of first delim in my chunk0 slice
    const int off1 = c0tot + (pre >> 16);       // rank of first delim in my chunk1 slice

    // ---- phase 1b: emit ordered delimiter positions from registers ----
    if (c0 > 0 && off0 < N_ - 1) {
        int o = off0;
        const int p = 4 * t;
        if (r0.x == DELIM_) { if (o < N_ - 1) s_dpos[o] = p;     ++o; }
        if (r0.y == DELIM_) { if (o < N_ - 1) s_dpos[o] = p + 1; ++o; }
        if (r0.z == DELIM_) { if (o < N_ - 1) s_dpos[o] = p + 2; ++o; }
        if (r0.w == DELIM_) { if (o < N_ - 1) s_dpos[o] = p + 3; ++o; }
    }
    if (c1 > 0 && off1 < N_ - 1) {
        int o = off1;
        const int p = 4 * T_ + 4 * t;
        if (r1.x == DELIM_) { if (o < N_ - 1) s_dpos[o] = p;     ++o; }
        if (r1.y == DELIM_) { if (o < N_ - 1) s_dpos[o] = p + 1; ++o; }
        if (r1.z == DELIM_) { if (o < N_ - 1) s_dpos[o] = p + 2; ++o; }
        if (r1.w == DELIM_) { if (o < N_ - 1) s_dpos[o] = p + 3; ++o; }
    }
    __syncthreads();

    // ---- phase 1c: chunk table ----
    if (t < N_) {
        const int k = t;
        const int mc = (m < N_ - 1) ? m : (N_ - 1);  // last used chunk index
        int start = 0, cl = 0;
        if (k <= mc) {
            start = (k == 0) ? 0 : (s_dpos[k - 1] + 1);
            const int end = (k < mc) ? s_dpos[k] : L_;  // rpad[L] = trailing DELIM
            const int size = end - start + 1;           // delimiter belongs to its chunk
            cl = (size <= 1) ? 0 : (size < S_ ? size : S_);  // lone delim -> all PAD
        }
        s_start[k] = start;
        s_cl[k] = cl;
    }
    __syncthreads();

    // ---- phase 2: wave w handles sentence k = i*NW_ + w (8 iterations) ----
    float* __restrict__ otp_b = otp + (size_t)b * N_ * S_;
    float* __restrict__ msk_b = mask + (size_t)b * N_ * S_;
    int doccnt = 0;
#pragma unroll
    for (int i = 0; i < (N_ / NW_); ++i) {
        const int k = i * NW_ + w;
        const int start = s_start[k];  // wave-uniform LDS broadcast
        const int cl = s_cl[k];
        const int s0 = lane * 4;
        float tf[4];
        int len = 0;
#pragma unroll
        for (int j = 0; j < 4; ++j) {
            const int e = s0 + j;
            int tok = 0;
            if (e < cl) {
                const int g = start + e;
                tok = (g < L_) ? row[g] : DELIM_;  // L1/L2 hit: row read in phase 1
            }
            tf[j] = (float)tok;
            len += __popcll(__ballot(tok != 0));  // wave-uniform nonzero count
        }

        *(float4*)(otp_b + (size_t)k * S_ + s0) =
            make_float4(tf[0], tf[1], tf[2], tf[3]);
        *(float4*)(msk_b + (size_t)k * S_ + s0) =
            make_float4(s0 < len ? 1.0f : 0.0f, s0 + 1 < len ? 1.0f : 0.0f,
                        s0 + 2 < len ? 1.0f : 0.0f, s0 + 3 < len ? 1.0f : 0.0f);
        doccnt += (len > 0);
    }

    // ---- len_doc: one LDS reduction per block, no atomics ----
    if (lane == 0) s_doc[w] = doccnt;
    __syncthreads();
    if (t == 0) {
        int d = 0;
#pragma unroll
        for (int i = 0; i < NW_; ++i) d += s_doc[i];
        len_doc[b] = (float)d;
    }
}

extern "C" void kernel_launch(void* const* d_in, const int* in_sizes, int n_in,
                              void* d_out, int out_size, void* d_ws, size_t ws_size,
                              hipStream_t stream) {
    const int* x = (const int*)d_in[0];
    float* out = (float*)d_out;

    // d_out layout (flat, return order): otp[B*N*S] | len_doc[B] | mask[B*N*S]
    float* otp = out;
    float* len_doc = out + (size_t)B_ * N_ * S_;
    float* mask = len_doc + B_;

    split_kernel<<<B_, T_, 0, stream>>>(x, otp, len_doc, mask);
}

// Round 7
// 141.707 us; speedup vs baseline: 1.0721x; 1.0055x over previous
//
#include <hip/hip_runtime.h>

#define B_ 512
#define L_ 8192
#define N_ 128
#define S_ 256
#define DELIM_ 5
#define T_ 1024          // 16 waves/block, 2 blocks/CU -> 32 waves/CU
#define NW_ (T_ / 64)

// One block per row.
// Phase 1: coalesced int4 row read -> registers AND LDS (ds_write_b128);
//          packed block scan -> ordered delimiter positions -> chunk table.
// Phase 2: one sentence per wave per iteration; tokens gathered from LDS
//          (stride-1, conflict-free; kills the ~200-cyc global gather latency
//          of R6), element layout e = 64*j + lane -> coalesced dword stores.
//          ballot+popc for len_sent. No atomics.
__global__ __launch_bounds__(T_) void split_kernel(const int* __restrict__ x,
                                                   float* __restrict__ otp,
                                                   float* __restrict__ len_doc,
                                                   float* __restrict__ mask) {
    const int b = blockIdx.x;
    const int t = threadIdx.x;
    const int lane = t & 63;
    const int w = t >> 6;
    const int* __restrict__ row = x + (size_t)b * L_;

    __shared__ __align__(16) int s_row[L_ + 1];  // row + virtual trailing DELIM
    __shared__ int s_wsum[NW_];
    __shared__ int s_dpos[N_ - 1];  // first 127 delimiter positions (tail merge)
    __shared__ int s_start[N_];
    __shared__ int s_cl[N_];        // copy length: 0 for empty/unused, else min(size, S)
    __shared__ int s_doc[NW_];

    // ---- phase 1a: coalesced int4 loads; stage into LDS; count delims ----
    const int4 r0 = ((const int4*)row)[t];        // tokens [4t, 4t+4)
    const int4 r1 = ((const int4*)row)[t + T_];   // tokens [4096+4t, ...)
    ((int4*)s_row)[t] = r0;                       // ds_write_b128, conflict-free
    ((int4*)s_row)[t + T_] = r1;
    if (t == 0) s_row[L_] = DELIM_;               // rpad[L]

    const int c0 = (r0.x == DELIM_) + (r0.y == DELIM_) + (r0.z == DELIM_) + (r0.w == DELIM_);
    const int c1 = (r1.x == DELIM_) + (r1.y == DELIM_) + (r1.z == DELIM_) + (r1.w == DELIM_);
    const int packed = c0 | (c1 << 16);

    // wave inclusive scan of packed counts
    int v = packed;
#pragma unroll
    for (int d = 1; d < 64; d <<= 1) {
        int n = __shfl_up(v, d, 64);
        if (lane >= d) v += n;
    }
    if (lane == 63) s_wsum[w] = v;
    __syncthreads();

    int woff = 0, tot = 0;
#pragma unroll
    for (int i = 0; i < NW_; ++i) {
        const int sv = s_wsum[i];
        if (i < w) woff += sv;
        tot += sv;
    }
    const int pre = woff + v - packed;          // exclusive prefix (packed)
    const int c0tot = tot & 0xffff;             // total delims in first half
    const int m = c0tot + (tot >> 16);          // total delims in row
    const int off0 = pre & 0xffff;
    const int off1 = c0tot + (pre >> 16);

    // ---- phase 1b: emit ordered delimiter positions from registers ----
    if (c0 > 0 && off0 < N_ - 1) {
        int o = off0;
        const int p = 4 * t;
        if (r0.x == DELIM_) { if (o < N_ - 1) s_dpos[o] = p;     ++o; }
        if (r0.y == DELIM_) { if (o < N_ - 1) s_dpos[o] = p + 1; ++o; }
        if (r0.z == DELIM_) { if (o < N_ - 1) s_dpos[o] = p + 2; ++o; }
        if (r0.w == DELIM_) { if (o < N_ - 1) s_dpos[o] = p + 3; ++o; }
    }
    if (c1 > 0 && off1 < N_ - 1) {
        int o = off1;
        const int p = 4 * T_ + 4 * t;
        if (r1.x == DELIM_) { if (o < N_ - 1) s_dpos[o] = p;     ++o; }
        if (r1.y == DELIM_) { if (o < N_ - 1) s_dpos[o] = p + 1; ++o; }
        if (r1.z == DELIM_) { if (o < N_ - 1) s_dpos[o] = p + 2; ++o; }
        if (r1.w == DELIM_) { if (o < N_ - 1) s_dpos[o] = p + 3; ++o; }
    }
    __syncthreads();

    // ---- phase 1c: chunk table ----
    if (t < N_) {
        const int k = t;
        const int mc = (m < N_ - 1) ? m : (N_ - 1);  // last used chunk index
        int start = 0, cl = 0;
        if (k <= mc) {
            start = (k == 0) ? 0 : (s_dpos[k - 1] + 1);
            const int end = (k < mc) ? s_dpos[k] : L_;  // rpad[L] = trailing DELIM
            const int size = end - start + 1;           // delimiter belongs to its chunk
            cl = (size <= 1) ? 0 : (size < S_ ? size : S_);  // lone delim -> all PAD
        }
        s_start[k] = start;
        s_cl[k] = cl;
    }
    __syncthreads();

    // ---- phase 2: wave w handles sentence k = i*NW_ + w (8 iterations) ----
    float* __restrict__ otp_b = otp + (size_t)b * N_ * S_;
    float* __restrict__ msk_b = mask + (size_t)b * N_ * S_;
    int doccnt = 0;
#pragma unroll
    for (int i = 0; i < (N_ / NW_); ++i) {
        const int k = i * NW_ + w;
        const int start = s_start[k];  // wave-uniform LDS broadcast
        const int cl = s_cl[k];
        float tf[4];
        int len = 0;
#pragma unroll
        for (int j = 0; j < 4; ++j) {
            const int e = 64 * j + lane;          // stride-1 LDS read, conflict-free
            const int tok = (e < cl) ? s_row[start + e] : 0;  // start+e <= L_ when e<cl
            tf[j] = (float)tok;
            len += __popcll(__ballot(tok != 0));  // wave-uniform nonzero count
        }
#pragma unroll
        for (int j = 0; j < 4; ++j) {
            const int e = 64 * j + lane;
            otp_b[(size_t)k * S_ + e] = tf[j];    // coalesced 256B dword store
            msk_b[(size_t)k * S_ + e] = (e < len) ? 1.0f : 0.0f;
        }
        doccnt += (len > 0);
    }

    // ---- len_doc: one LDS reduction per block, no atomics ----
    if (lane == 0) s_doc[w] = doccnt;
    __syncthreads();
    if (t == 0) {
        int d = 0;
#pragma unroll
        for (int i = 0; i < NW_; ++i) d += s_doc[i];
        len_doc[b] = (float)d;
    }
}

extern "C" void kernel_launch(void* const* d_in, const int* in_sizes, int n_in,
                              void* d_out, int out_size, void* d_ws, size_t ws_size,
                              hipStream_t stream) {
    const int* x = (const int*)d_in[0];
    float* out = (float*)d_out;

    // d_out layout (flat, return order): otp[B*N*S] | len_doc[B] | mask[B*N*S]
    float* otp = out;
    float* len_doc = out + (size_t)B_ * N_ * S_;
    float* mask = len_doc + B_;

    split_kernel<<<B_, T_, 0, stream>>>(x, otp, len_doc, mask);
}